// Round 11
// baseline (85.797 us; speedup 1.0000x reference)
//
#include <hip/hip_runtime.h>
#include <stdint.h>

// SortNode2Pin: per-node argmin over CSR pin slices by sorted_pin_map key.
// v11: v10 structure + real MLP.
//  - __launch_bounds__(256,2): VGPR cap 128 (v10's bare launch_bounds forced
//    <=32 VGPR -> compiler serialized the 16 staging gathers into ~4-deep).
//  - Phase 1: all 16 key4 word-loads issued into an independent register
//    array before any nibble extraction (16 outstanding loads per thread).

typedef int iv4 __attribute__((ext_vector_type(4)));

#define NPB 1024   // nodes per block
#define NT  256    // threads per block
#define SEGS 4     // segments per thread
#define CAP 4608   // slots capacity: mean 4096, sd ~128 -> +4 sigma; fallback covers rest
#define PINMASK 0x7FFFFFu

__global__ void build_key4_kernel(const int* __restrict__ key,
                                  uint32_t* __restrict__ key4,
                                  int num_pins, int shift) {
    int t = blockIdx.x * blockDim.x + threadIdx.x;
    int base = t * 8;
    if (base >= num_pins) return;
    if (base + 8 <= num_pins) {
        const iv4* kp = (const iv4*)(key + base);
        iv4 a = __builtin_nontemporal_load(kp);
        iv4 b = __builtin_nontemporal_load(kp + 1);
        uint32_t w = 0;
        w |= (((uint32_t)a.x >> shift) & 15u) << 0;
        w |= (((uint32_t)a.y >> shift) & 15u) << 4;
        w |= (((uint32_t)a.z >> shift) & 15u) << 8;
        w |= (((uint32_t)a.w >> shift) & 15u) << 12;
        w |= (((uint32_t)b.x >> shift) & 15u) << 16;
        w |= (((uint32_t)b.y >> shift) & 15u) << 20;
        w |= (((uint32_t)b.z >> shift) & 15u) << 24;
        w |= (((uint32_t)b.w >> shift) & 15u) << 28;
        __builtin_nontemporal_store(w, key4 + t);
    } else {
        uint32_t w = 0;
        for (int j = 0; base + j < num_pins; ++j) {
            uint32_t k = (uint32_t)key[base + j];
            w |= ((k >> shift) & 15u) << (4 * j);
        }
        __builtin_nontemporal_store(w, key4 + t);
    }
}

__device__ __forceinline__ uint32_t nib_of(const uint32_t* key4, uint32_t p) {
    uint32_t w = key4[p >> 3];
    return (w >> ((p & 7u) * 4u)) & 15u;
}

__device__ __forceinline__ iv4 load_chunk(const int* __restrict__ n2p,
                                          int jal, int jbeg, int jend, int c) {
    int j0 = jal + (c << 2);
    if (j0 >= jbeg && j0 + 4 <= jend) {
        return __builtin_nontemporal_load((const iv4*)(n2p + j0));
    }
    iv4 r;
    #pragma unroll
    for (int e = 0; e < 4; ++e) {
        int j = j0 + e;
        r[e] = (j >= jbeg && j < jend) ? __builtin_nontemporal_load(n2p + j)
                                       : -1;   // sentinel
    }
    return r;
}

// branch-free 3-smallest insert
__device__ __forceinline__ void upd3(uint32_t sp, uint32_t& m1, uint32_t& m2,
                                     uint32_t& m3) {
    uint32_t a = min(sp, m1);
    uint32_t b = max(sp, m1);
    uint32_t c = min(b, m2);
    uint32_t d = max(b, m2);
    m1 = a; m2 = c; m3 = min(d, m3);
}

__device__ __forceinline__ void scan_mins(const uint32_t* slot, int s, int e,
                                          uint32_t& m1, uint32_t& m2, uint32_t& m3) {
    m1 = ~0u; m2 = ~0u; m3 = ~0u;
    for (int q = (s & ~3); q < e; q += 4) {
        iv4 v = *(const iv4*)(slot + q);       // ds_read_b128
        #pragma unroll
        for (int u = 0; u < 4; ++u) {
            int j = q + u;
            uint32_t sp = (uint32_t)v[u];
            sp = (j >= s && j < e) ? sp : ~0u; // mask foreign/pad slots
            upd3(sp, m1, m2, m3);
        }
    }
}

__global__ __launch_bounds__(NT, 2) void SortNode2Pin_stage_kernel(
        const int* __restrict__ starts,
        const int* __restrict__ n2p,
        const int* __restrict__ key,
        const uint32_t* __restrict__ key4,
        int* __restrict__ out,
        int num_nodes) {
    __shared__ __align__(16) uint32_t slot[CAP + 8];

    int t = threadIdx.x;
    int i0 = blockIdx.x * NPB;

    // block slot range (uniform -> scalar loads)
    int iend = i0 + NPB; if (iend > num_nodes) iend = num_nodes;
    int jbeg0 = starts[i0 < num_nodes ? i0 : num_nodes];
    int jend0 = starts[iend];
    int range = jend0 - jbeg0;

    // per-thread segment bounds (coalesced, L1-served)
    int sS[SEGS], eS[SEGS];
    #pragma unroll
    for (int k = 0; k < SEGS; ++k) {
        int ia = i0 + k * NT + t;  if (ia > num_nodes) ia = num_nodes;
        int ib = ia + 1;           if (ib > num_nodes) ib = num_nodes;
        sS[k] = starts[ia];
        eS[k] = starts[ib];
    }

    if (range <= CAP) {
        // ---- phase 1: staging with 16 independent gathers in flight -----
        int jal = jbeg0 & ~3;
        int nch = (jend0 - jal + 3) >> 2;
        int c = t;
        for (; c + 3 * NT < nch; c += 4 * NT) {
            // step 1: four coalesced pin-chunk loads
            iv4 p0 = load_chunk(n2p, jal, jbeg0, jend0, c);
            iv4 p1 = load_chunk(n2p, jal, jbeg0, jend0, c + NT);
            iv4 p2 = load_chunk(n2p, jal, jbeg0, jend0, c + 2 * NT);
            iv4 p3 = load_chunk(n2p, jal, jbeg0, jend0, c + 3 * NT);
            uint32_t pin[16];
            #pragma unroll
            for (int u = 0; u < 4; ++u) {
                pin[u]      = (uint32_t)p0[u];
                pin[u + 4]  = (uint32_t)p1[u];
                pin[u + 8]  = (uint32_t)p2[u];
                pin[u + 12] = (uint32_t)p3[u];
            }
            // step 2: issue ALL 16 table-word loads (independent, no uses)
            uint32_t wrd[16];
            #pragma unroll
            for (int u = 0; u < 16; ++u)
                wrd[u] = key4[(pin[u] & PINMASK) >> 3];   // mask keeps sentinel in-bounds
            // step 3: extract + pack (consumes loads in order)
            uint32_t sv[16];
            #pragma unroll
            for (int u = 0; u < 16; ++u) {
                uint32_t nib = (wrd[u] >> ((pin[u] & 7u) * 4u)) & 15u;
                sv[u] = ((int)pin[u] < 0) ? 0xFFFFFFFFu : ((nib << 23) | pin[u]);
            }
            iv4 w0, w1, w2, w3;
            #pragma unroll
            for (int u = 0; u < 4; ++u) {
                w0[u] = (int)sv[u];
                w1[u] = (int)sv[u + 4];
                w2[u] = (int)sv[u + 8];
                w3[u] = (int)sv[u + 12];
            }
            *(iv4*)&slot[(c         ) << 2] = w0;
            *(iv4*)&slot[(c +     NT) << 2] = w1;
            *(iv4*)&slot[(c + 2 * NT) << 2] = w2;
            *(iv4*)&slot[(c + 3 * NT) << 2] = w3;
        }
        for (; c < nch; c += NT) {
            iv4 pa = load_chunk(n2p, jal, jbeg0, jend0, c);
            iv4 wa;
            #pragma unroll
            for (int u = 0; u < 4; ++u) {
                uint32_t p = (uint32_t)pa[u];
                uint32_t wv = key4[(p & PINMASK) >> 3];
                uint32_t nib = (wv >> ((p & 7u) * 4u)) & 15u;
                wa[u] = ((int)p < 0) ? (int)0xFFFFFFFFu : (int)((nib << 23) | p);
            }
            *(iv4*)&slot[c << 2] = wa;
        }
        __syncthreads();

        // ---- phase 2a: 3-min scans for all 4 segments (LDS only) --------
        uint32_t M1[SEGS], M2[SEGS], M3[SEGS];
        #pragma unroll
        for (int k = 0; k < SEGS; ++k)
            scan_mins(slot, sS[k] - jal, eS[k] - jal, M1[k], M2[k], M3[k]);

        // ---- phase 2b: classify; batch tie gathers ----------------------
        int res[SEGS];
        int pa2[SEGS], pb2[SEGS];
        bool two[SEGS], multi[SEGS];
        #pragma unroll
        for (int k = 0; k < SEGS; ++k) {
            two[k] = false; multi[k] = false;
            pa2[k] = 0; pb2[k] = 0;
            uint32_t b1 = M1[k] >> 23;
            if (eS[k] <= sS[k]) {
                res[k] = 0;                                   // empty node
            } else if ((M2[k] >> 23) != b1) {
                res[k] = (int)(M1[k] & PINMASK);              // unique min nib
            } else if ((M3[k] >> 23) != b1) {
                two[k] = true;                                // exactly 2 tied
                pa2[k] = (int)(M1[k] & PINMASK);
                pb2[k] = (int)(M2[k] & PINMASK);
                res[k] = 0;
            } else {
                multi[k] = true;                              // >=3 tied (rare)
                res[k] = 0;
            }
        }
        int ka[SEGS], kb[SEGS];
        #pragma unroll
        for (int k = 0; k < SEGS; ++k) {
            ka[k] = 0; kb[k] = 0;
            if (two[k]) { ka[k] = key[pa2[k]]; kb[k] = key[pb2[k]]; }
        }
        #pragma unroll
        for (int k = 0; k < SEGS; ++k)
            if (two[k]) res[k] = ka[k] < kb[k] ? pa2[k] : pb2[k];

        // ---- phase 2c: >=3-way ties (rare): masked exact scan -----------
        #pragma unroll
        for (int k = 0; k < SEGS; ++k) {
            if (multi[k]) {
                uint32_t b1 = M1[k] >> 23;
                int bk = 0x7fffffff, r = 0;
                for (int q = sS[k] - jal; q < eS[k] - jal; ++q) {
                    uint32_t sp = slot[q];
                    if ((sp >> 23) == b1) {
                        int p = (int)(sp & PINMASK);
                        int kk = key[p];
                        if (kk < bk) { bk = kk; r = p; }
                    }
                }
                res[k] = r;
            }
        }

        // ---- store ------------------------------------------------------
        #pragma unroll
        for (int k = 0; k < SEGS; ++k) {
            int node = i0 + k * NT + t;
            if (node < num_nodes)
                __builtin_nontemporal_store(res[k], out + node);
        }
    } else {
        // ---- pathological block range: per-thread lazy-tie scan ---------
        for (int idx = t; idx < NPB; idx += NT) {
            int node = i0 + idx;
            if (node >= num_nodes) break;
            int s = starts[node], e = starts[node + 1];
            int mv = 16, bp = 0, bk = -1;
            for (int j = s; j < e; ++j) {
                uint32_t p = (uint32_t)n2p[j];
                int n = (int)nib_of(key4, p);
                if (n > mv) continue;
                if (n < mv) { mv = n; bp = (int)p; bk = -1; }
                else {
                    if (bk < 0) bk = key[bp];
                    int k = key[p];
                    if (k < bk) { bk = k; bp = (int)p; }
                }
            }
            __builtin_nontemporal_store(bp, out + node);
        }
    }
}

// Fallback if workspace too small or pins don't fit the 23-bit packing.
__global__ void SortNode2Pin_direct_kernel(const int* __restrict__ starts,
                                           const int* __restrict__ n2p,
                                           const int* __restrict__ key,
                                           int* __restrict__ out,
                                           int num_nodes) {
    int i = blockIdx.x * blockDim.x + threadIdx.x;
    if (i >= num_nodes) return;
    int s = starts[i];
    int e = starts[i + 1];
    int best_pin = 0;
    int best_key = 0x7fffffff;
    for (int j = s; j < e; ++j) {
        int p = n2p[j];
        int k = key[p];
        if (k < best_key) { best_key = k; best_pin = p; }
    }
    out[i] = best_pin;
}

extern "C" void kernel_launch(void* const* d_in, const int* in_sizes, int n_in,
                              void* d_out, int out_size, void* d_ws, size_t ws_size,
                              hipStream_t stream) {
    const int* starts = (const int*)d_in[0];   // [num_nodes+1]
    const int* n2p    = (const int*)d_in[1];   // [num_pins]
    const int* key    = (const int*)d_in[2];   // [num_pins]
    int num_nodes = out_size;
    int num_pins  = in_sizes[1];

    size_t key4_words = (size_t)((num_pins + 7) / 8);
    size_t need = key4_words * sizeof(uint32_t);

    if (ws_size >= need && num_pins < (1 << 23)) {
        int bits = 32 - __builtin_clz((unsigned)(num_pins - 1));  // ceil(log2)
        int shift = bits > 4 ? bits - 4 : 0;
        uint32_t* key4 = (uint32_t*)d_ws;

        int g1 = (int)((key4_words + NT - 1) / NT);
        build_key4_kernel<<<g1, NT, 0, stream>>>(key, key4, num_pins, shift);

        int g2 = (num_nodes + NPB - 1) / NPB;
        SortNode2Pin_stage_kernel<<<g2, NT, 0, stream>>>(
            starts, n2p, key, key4, (int*)d_out, num_nodes);
    } else {
        int grid = (num_nodes + 255) / 256;
        SortNode2Pin_direct_kernel<<<grid, 256, 0, stream>>>(
            starts, n2p, key, (int*)d_out, num_nodes);
    }
}